// Round 1
// baseline (2417.766 us; speedup 1.0000x reference)
//
#include <hip/hip_runtime.h>
#include <hip/hip_bf16.h>

#define NB 8
#define CAP 128
#define NSLICE 16
#define NFEAT 704

// ---------------- setup kernels ----------------

__global__ void count_edges(const int* __restrict__ ei, int E, int* __restrict__ cnt) {
    int e = blockIdx.x * blockDim.x + threadIdx.x;
    if (e < E) atomicAdd(&cnt[ei[E + e]], 1);
}

__global__ void compute_dinv(const int* __restrict__ cnt, float* __restrict__ dinv, int n) {
    int v = blockIdx.x * blockDim.x + threadIdx.x;
    if (v < n) dinv[v] = rsqrtf((float)(cnt[v] + 1));  // +1 self-loop; always > 0
}

__global__ void fill_edges(const int* __restrict__ ei, int E, const float* __restrict__ dinv,
                           int* __restrict__ cursor, int2* __restrict__ pairs) {
    int e = blockIdx.x * blockDim.x + threadIdx.x;
    if (e < E) {
        int r = ei[e], c = ei[E + e];
        int pos = atomicAdd(&cursor[c], 1);
        if (pos < CAP) {
            float w = dinv[r] * dinv[c];
            pairs[(size_t)c * CAP + pos] = make_int2(r, __float_as_int(w));
        }
    }
}

__global__ void batch_count(const int* __restrict__ batch, int n, int* __restrict__ bcnt) {
    int i = blockIdx.x * blockDim.x + threadIdx.x;
    if (i < n) atomicAdd(&bcnt[batch[i]], 1);
}

__global__ void batch_offsets(const int* __restrict__ bcnt, int* __restrict__ boff) {
    if (threadIdx.x == 0 && blockIdx.x == 0) {
        int acc = 0;
        boff[0] = 0;
        for (int b = 0; b < NB; ++b) { acc += bcnt[b]; boff[b + 1] = acc; }
    }
}

// ---------------- cascade ----------------
// h_out[v] = 0.5*((1 + dinv[v]^2) * h_in[v] + sum_e w_e * h_in[src_e])
// one wave per node; lane covers F/64 consecutive floats.

template <int F>
__global__ __launch_bounds__(256) void cascade_step(
    const float* __restrict__ h_in, float* __restrict__ h_out,
    const int2* __restrict__ pairs, const int* __restrict__ cnt,
    const float* __restrict__ dinv, int n)
{
    constexpr int VEC = F / 64;
    int wave = (blockIdx.x * blockDim.x + threadIdx.x) >> 6;
    int lane = threadIdx.x & 63;
    if (wave >= n) return;
    int node = wave;
    int deg = cnt[node];
    float dv = dinv[node];
    float selfw = dv * dv;

    const float* hib = h_in + (size_t)node * F + lane * VEC;
    float hv[VEC], acc[VEC];
    if constexpr (VEC == 4) {
        float4 t = *reinterpret_cast<const float4*>(hib);
        hv[0] = t.x; hv[1] = t.y; hv[2] = t.z; hv[3] = t.w;
    } else {
        hv[0] = hib[0];
    }
#pragma unroll
    for (int i = 0; i < VEC; ++i) acc[i] = 0.f;

    const int2* pb = pairs + (size_t)node * CAP;
    for (int base = 0; base < deg; base += 64) {
        int mysrc = 0; float myw = 0.f;
        int idx = base + lane;
        if (idx < deg) {
            int2 p = pb[idx];
            mysrc = p.x; myw = __int_as_float(p.y);
        }
        int m = min(64, deg - base);
        for (int j = 0; j < m; ++j) {
            int s = __shfl(mysrc, j, 64);
            float w = __shfl(myw, j, 64);
            const float* g = h_in + (size_t)s * F + lane * VEC;
            if constexpr (VEC == 4) {
                float4 gv = *reinterpret_cast<const float4*>(g);
                acc[0] += w * gv.x; acc[1] += w * gv.y;
                acc[2] += w * gv.z; acc[3] += w * gv.w;
            } else {
                acc[0] += w * g[0];
            }
        }
    }

    float* ob = h_out + (size_t)node * F + lane * VEC;
#pragma unroll
    for (int i = 0; i < VEC; ++i) ob[i] = 0.5f * ((1.f + selfw) * hv[i] + acc[i]);
}

// ---------------- snapshot / diff ----------------

__global__ void copyk(const float* __restrict__ a, float* __restrict__ b, int n) {
    int i = blockIdx.x * blockDim.x + threadIdx.x;
    if (i < n) b[i] = a[i];
}

// level 1: elements = N*64; S1 layout [n][w][c] (stride 256)
__global__ void diff1(const float* __restrict__ cur, float* __restrict__ prev,
                      float* __restrict__ S1, int w, int n) {
    int i = blockIdx.x * blockDim.x + threadIdx.x;
    if (i >= n) return;
    float c = cur[i], p = prev[i];
    prev[i] = c;
    int node = i >> 6, ch = i & 63;
    S1[(size_t)node * 256 + w * 64 + ch] = fabsf(c - p);
}

// level 2: elements = N*256 (f = b*64 + c); S2 layout [n][j'][c] (stride 384)
__global__ void diff2(const float* __restrict__ cur, float* __restrict__ prev,
                      float* __restrict__ S2, int w, int basej, int n) {
    int i = blockIdx.x * blockDim.x + threadIdx.x;
    if (i >= n) return;
    float c = cur[i], p = prev[i];
    prev[i] = c;
    int f = i & 255;
    int b = f >> 6, ch = f & 63, node = i >> 8;
    if (b < w) S2[(size_t)node * 384 + (basej + b) * 64 + ch] = fabsf(c - p);
}

// ---------------- moments ----------------

__global__ __launch_bounds__(256) void moments_k(
    const float* __restrict__ x, const float* __restrict__ S1, const float* __restrict__ S2,
    const int* __restrict__ boff, double* __restrict__ mom)
{
    int bid = blockIdx.x;                 // b * (3*NSLICE) + chunk * NSLICE + slice
    int slice = bid % NSLICE;
    int chunk = (bid / NSLICE) % 3;
    int b = bid / (3 * NSLICE);
    int f = chunk * 256 + threadIdx.x;
    if (f >= NFEAT) return;
    int k = f >> 6, c = f & 63;
    const float* base; int stride;
    if (k == 0)      { base = x  + c;                stride = 64;  }
    else if (k <= 4) { base = S1 + (k - 1) * 64 + c; stride = 256; }
    else             { base = S2 + (k - 5) * 64 + c; stride = 384; }

    int s0 = boff[b], s1e = boff[b + 1];
    int cnt = s1e - s0;
    int per = (cnt + NSLICE - 1) / NSLICE;
    int i0 = s0 + slice * per;
    int i1 = min(s1e, i0 + per);

    double a1 = 0, a2 = 0, a3 = 0, a4 = 0;
    for (int i = i0; i < i1; ++i) {
        double v = (double)base[(size_t)i * stride];
        double v2 = v * v;
        a1 += v; a2 += v2; a3 += v2 * v; a4 += v2 * v2;
    }
    double* m = mom + ((size_t)b * NFEAT + f) * 4;
    atomicAdd(&m[0], a1);
    atomicAdd(&m[1], a2);
    atomicAdd(&m[2], a3);
    atomicAdd(&m[3], a4);
}

__global__ void finalize_k(const double* __restrict__ mom, const int* __restrict__ bcnt,
                           const float* __restrict__ W, float* __restrict__ out) {
    int i = blockIdx.x * blockDim.x + threadIdx.x;
    if (i < NB * NFEAT) {
        int b = i / NFEAT, f = i % NFEAT;
        double cn = (double)max(bcnt[b], 1);
        const double* m = mom + ((size_t)b * NFEAT + f) * 4;
        double mean = m[0] / cn;
        double e2 = m[1] / cn, e3 = m[2] / cn, e4 = m[3] / cn;
        double var = e2 - mean * mean;
        double m3 = e3 - 3.0 * mean * e2 + 2.0 * mean * mean * mean;
        double m4 = e4 - 4.0 * mean * e3 + 6.0 * mean * mean * e2 - 3.0 * mean * mean * mean * mean;
        float skew, kurt;
        if (var > 0.0) {
            double vs = var * sqrt(var);
            skew = (float)(m3 / vs);
            kurt = (float)(m4 / (var * var));
        } else {
            skew = 0.f; kurt = -3.f;
        }
        out[b * 2816 + f]        = (float)mean;
        out[b * 2816 + 704 + f]  = (float)var;
        out[b * 2816 + 1408 + f] = skew;
        out[b * 2816 + 2112 + f] = kurt;
    } else if (i < NB * NFEAT + 68) {
        int j = i - NB * NFEAT;
        out[NB * 2816 + j] = W[j];
    }
}

// ---------------- launch ----------------

extern "C" void kernel_launch(void* const* d_in, const int* in_sizes, int n_in,
                              void* d_out, int out_size, void* d_ws, size_t ws_size,
                              hipStream_t stream) {
    const float* x     = (const float*)d_in[0];
    const int*   ei    = (const int*)d_in[1];
    const int*   batch = (const int*)d_in[2];
    const float* W     = (const float*)d_in[3];
    int N = in_sizes[0] / 64;   // 20000
    int E = in_sizes[1] / 2;    // 640000
    float* out = (float*)d_out;

    char* p = (char*)d_ws;
    auto alloc = [&](size_t bytes) { char* r = p; p += (bytes + 255) & ~255ULL; return r; };
    float* dinv  = (float*)alloc((size_t)N * 4);
    int*   cnt   = (int*)alloc((size_t)N * 4);
    int*   cursor= (int*)alloc((size_t)N * 4);
    int*   bcnt  = (int*)alloc(NB * 4);
    int*   boff  = (int*)alloc((NB + 1) * 4);
    double* mom  = (double*)alloc((size_t)NB * NFEAT * 4 * 8);
    int2*  pairs = (int2*)alloc((size_t)N * CAP * 8);
    float* S1    = (float*)alloc((size_t)N * 256 * 4);
    float* S2    = (float*)alloc((size_t)N * 384 * 4);
    float* bufA  = (float*)alloc((size_t)N * 256 * 4);
    float* bufB  = (float*)alloc((size_t)N * 256 * 4);
    float* prev  = (float*)alloc((size_t)N * 256 * 4);

    hipMemsetAsync(cnt, 0, (size_t)N * 4, stream);
    hipMemsetAsync(cursor, 0, (size_t)N * 4, stream);
    hipMemsetAsync(bcnt, 0, NB * 4, stream);
    hipMemsetAsync(mom, 0, (size_t)NB * NFEAT * 4 * 8, stream);

    count_edges<<<(E + 255) / 256, 256, 0, stream>>>(ei, E, cnt);
    compute_dinv<<<(N + 255) / 256, 256, 0, stream>>>(cnt, dinv, N);
    fill_edges<<<(E + 255) / 256, 256, 0, stream>>>(ei, E, dinv, cursor, pairs);
    batch_count<<<(N + 255) / 256, 256, 0, stream>>>(batch, N, bcnt);
    batch_offsets<<<1, 64, 0, stream>>>(bcnt, boff);

    int cgrid = (N + 3) / 4;  // 4 waves (nodes) per 256-thread block

    // ---- level 1: F=64, h0 = x; snapshots at 1,2,4,8,16 ----
    const float* hin = x;
    for (int s = 1; s <= 16; ++s) {
        float* ho = (s & 1) ? bufA : bufB;
        cascade_step<64><<<cgrid, 256, 0, stream>>>(hin, ho, pairs, cnt, dinv, N);
        hin = ho;
        if (s == 1) {
            copyk<<<(N * 64 + 255) / 256, 256, 0, stream>>>(ho, prev, N * 64);
        } else if (s == 2 || s == 4 || s == 8 || s == 16) {
            int w = (s == 2) ? 0 : (s == 4) ? 1 : (s == 8) ? 2 : 3;
            diff1<<<(N * 64 + 255) / 256, 256, 0, stream>>>(ho, prev, S1, w, N * 64);
        }
    }

    // ---- level 2: F=256, h0 = S1; diffs at 4,8,16 (w=1,2,3), snapshot base at 2 ----
    hin = S1;
    for (int s = 1; s <= 16; ++s) {
        float* ho = (s & 1) ? bufA : bufB;
        cascade_step<256><<<cgrid, 256, 0, stream>>>(hin, ho, pairs, cnt, dinv, N);
        hin = ho;
        if (s == 2) {
            copyk<<<(N * 256 + 255) / 256, 256, 0, stream>>>(ho, prev, N * 256);
        } else if (s == 4 || s == 8 || s == 16) {
            int w = (s == 4) ? 1 : (s == 8) ? 2 : 3;
            int basej = (w == 1) ? 0 : (w == 2) ? 1 : 3;
            diff2<<<(N * 256 + 255) / 256, 256, 0, stream>>>(ho, prev, S2, w, basej, N * 256);
        }
    }

    moments_k<<<NB * 3 * NSLICE, 256, 0, stream>>>(x, S1, S2, boff, mom);

    int fin_threads = NB * NFEAT + 68;
    finalize_k<<<(fin_threads + 255) / 256, 256, 0, stream>>>(mom, bcnt, W, out);
}

// Round 2
// 1851.248 us; speedup vs baseline: 1.3060x; 1.3060x over previous
//
#include <hip/hip_runtime.h>
#include <hip/hip_bf16.h>

#define NB 8
#define CAP 128
#define NSLICE 16
#define NFEAT 704

// ---------------- setup kernels ----------------

__global__ void count_edges(const int* __restrict__ ei, int E, int* __restrict__ cnt) {
    int e = blockIdx.x * blockDim.x + threadIdx.x;
    if (e < E) atomicAdd(&cnt[ei[E + e]], 1);
}

__global__ void compute_dinv(const int* __restrict__ cnt, float* __restrict__ dinv, int n) {
    int v = blockIdx.x * blockDim.x + threadIdx.x;
    if (v < n) dinv[v] = rsqrtf((float)(cnt[v] + 1));  // +1 self-loop; always > 0
}

__global__ void fill_edges(const int* __restrict__ ei, int E, const float* __restrict__ dinv,
                           int* __restrict__ cursor, int2* __restrict__ pairs) {
    int e = blockIdx.x * blockDim.x + threadIdx.x;
    if (e < E) {
        int r = ei[e], c = ei[E + e];
        int pos = atomicAdd(&cursor[c], 1);
        if (pos < CAP) {
            float w = dinv[r] * dinv[c];
            pairs[(size_t)c * CAP + pos] = make_int2(r, __float_as_int(w));
        }
    }
}

// batch is SORTED: find boundaries, no atomics. boff[b] = first index with batch >= b.
__global__ void batch_bounds(const int* __restrict__ batch, int n, int* __restrict__ boff) {
    int i = blockIdx.x * blockDim.x + threadIdx.x;
    if (i >= n) return;
    int b = batch[i];
    int pb = (i == 0) ? -1 : batch[i - 1];
    for (int k = pb + 1; k <= b; ++k) boff[k] = i;
    if (i == n - 1) {
        for (int k = b + 1; k <= NB; ++k) boff[k] = n;
    }
}

// ---------------- cascade ----------------
// h_out[v] = 0.5*((1 + dinv[v]^2) * h_in[v] + sum_e w_e * h_in[src_e])
// one wave per node; lane covers F/64 consecutive floats.
// Edge loop software-pipelined: batch shfls, then UNROLL independent gathers
// in flight before the first consuming FMA (staged vmcnt waits).

template <int F>
__global__ __launch_bounds__(256) void cascade_step(
    const float* __restrict__ h_in, float* __restrict__ h_out,
    const int2* __restrict__ pairs, const int* __restrict__ cnt,
    const float* __restrict__ dinv, int n)
{
    constexpr int VEC = F / 64;
    int wave = (blockIdx.x * blockDim.x + threadIdx.x) >> 6;
    int lane = threadIdx.x & 63;
    if (wave >= n) return;
    int node = wave;
    int deg = cnt[node];
    float dv = dinv[node];
    float selfw = dv * dv;

    const float* hib = h_in + (size_t)node * F + lane * VEC;
    float hv[VEC];
    if constexpr (VEC == 4) {
        float4 t = *reinterpret_cast<const float4*>(hib);
        hv[0] = t.x; hv[1] = t.y; hv[2] = t.z; hv[3] = t.w;
    } else {
        hv[0] = hib[0];
    }

    const int2* pb = pairs + (size_t)node * CAP;

    if constexpr (VEC == 1) {
        float acc0 = 0.f, acc1 = 0.f, acc2 = 0.f, acc3 = 0.f;
        for (int base = 0; base < deg; base += 64) {
            int mysrc = 0; float myw = 0.f;
            int idx = base + lane;
            if (idx < deg) {
                int2 p = pb[idx];
                mysrc = p.x; myw = __int_as_float(p.y);
            }
            int m = min(64, deg - base);
            int j = 0;
            for (; j + 8 <= m; j += 8) {
                float g[8], w[8];
#pragma unroll
                for (int u = 0; u < 8; ++u) {
                    int s = __shfl(mysrc, j + u, 64);
                    w[u] = __shfl(myw, j + u, 64);
                    g[u] = h_in[(size_t)s * 64 + lane];
                }
                acc0 += w[0] * g[0]; acc1 += w[1] * g[1];
                acc2 += w[2] * g[2]; acc3 += w[3] * g[3];
                acc0 += w[4] * g[4]; acc1 += w[5] * g[5];
                acc2 += w[6] * g[6]; acc3 += w[7] * g[7];
            }
            for (; j < m; ++j) {
                int s = __shfl(mysrc, j, 64);
                float w = __shfl(myw, j, 64);
                acc0 += w * h_in[(size_t)s * 64 + lane];
            }
        }
        float acc = (acc0 + acc1) + (acc2 + acc3);
        h_out[(size_t)node * 64 + lane] = 0.5f * ((1.f + selfw) * hv[0] + acc);
    } else {
        float acc[4] = {0.f, 0.f, 0.f, 0.f};
        for (int base = 0; base < deg; base += 64) {
            int mysrc = 0; float myw = 0.f;
            int idx = base + lane;
            if (idx < deg) {
                int2 p = pb[idx];
                mysrc = p.x; myw = __int_as_float(p.y);
            }
            int m = min(64, deg - base);
            int j = 0;
            for (; j + 4 <= m; j += 4) {
                float4 g[4]; float w[4];
#pragma unroll
                for (int u = 0; u < 4; ++u) {
                    int s = __shfl(mysrc, j + u, 64);
                    w[u] = __shfl(myw, j + u, 64);
                    g[u] = *reinterpret_cast<const float4*>(h_in + (size_t)s * 256 + lane * 4);
                }
#pragma unroll
                for (int u = 0; u < 4; ++u) {
                    acc[0] += w[u] * g[u].x; acc[1] += w[u] * g[u].y;
                    acc[2] += w[u] * g[u].z; acc[3] += w[u] * g[u].w;
                }
            }
            for (; j < m; ++j) {
                int s = __shfl(mysrc, j, 64);
                float w = __shfl(myw, j, 64);
                float4 g = *reinterpret_cast<const float4*>(h_in + (size_t)s * 256 + lane * 4);
                acc[0] += w * g.x; acc[1] += w * g.y;
                acc[2] += w * g.z; acc[3] += w * g.w;
            }
        }
        float* ob = h_out + (size_t)node * 256 + lane * 4;
#pragma unroll
        for (int i = 0; i < 4; ++i) ob[i] = 0.5f * ((1.f + selfw) * hv[i] + acc[i]);
    }
}

// ---------------- snapshot / diff ----------------

__global__ void copyk(const float* __restrict__ a, float* __restrict__ b, int n) {
    int i = blockIdx.x * blockDim.x + threadIdx.x;
    if (i < n) b[i] = a[i];
}

// level 1: elements = N*64; S1 layout [n][w][c] (stride 256)
__global__ void diff1(const float* __restrict__ cur, float* __restrict__ prev,
                      float* __restrict__ S1, int w, int n) {
    int i = blockIdx.x * blockDim.x + threadIdx.x;
    if (i >= n) return;
    float c = cur[i], p = prev[i];
    prev[i] = c;
    int node = i >> 6, ch = i & 63;
    S1[(size_t)node * 256 + w * 64 + ch] = fabsf(c - p);
}

// level 2: elements = N*256 (f = b*64 + c); S2 layout [n][j'][c] (stride 384)
__global__ void diff2(const float* __restrict__ cur, float* __restrict__ prev,
                      float* __restrict__ S2, int w, int basej, int n) {
    int i = blockIdx.x * blockDim.x + threadIdx.x;
    if (i >= n) return;
    float c = cur[i], p = prev[i];
    prev[i] = c;
    int f = i & 255;
    int b = f >> 6, ch = f & 63, node = i >> 8;
    if (b < w) S2[(size_t)node * 384 + (basej + b) * 64 + ch] = fabsf(c - p);
}

// ---------------- moments ----------------

__global__ __launch_bounds__(256) void moments_k(
    const float* __restrict__ x, const float* __restrict__ S1, const float* __restrict__ S2,
    const int* __restrict__ boff, double* __restrict__ mom)
{
    int bid = blockIdx.x;                 // b * (3*NSLICE) + chunk * NSLICE + slice
    int slice = bid % NSLICE;
    int chunk = (bid / NSLICE) % 3;
    int b = bid / (3 * NSLICE);
    int f = chunk * 256 + threadIdx.x;
    if (f >= NFEAT) return;
    int k = f >> 6, c = f & 63;
    const float* base; int stride;
    if (k == 0)      { base = x  + c;                stride = 64;  }
    else if (k <= 4) { base = S1 + (k - 1) * 64 + c; stride = 256; }
    else             { base = S2 + (k - 5) * 64 + c; stride = 384; }

    int s0 = boff[b], s1e = boff[b + 1];
    int cnt = s1e - s0;
    int per = (cnt + NSLICE - 1) / NSLICE;
    int i0 = s0 + slice * per;
    int i1 = min(s1e, i0 + per);

    double a1 = 0, a2 = 0, a3 = 0, a4 = 0;
    for (int i = i0; i < i1; ++i) {
        double v = (double)base[(size_t)i * stride];
        double v2 = v * v;
        a1 += v; a2 += v2; a3 += v2 * v; a4 += v2 * v2;
    }
    double* m = mom + ((size_t)b * NFEAT + f) * 4;
    atomicAdd(&m[0], a1);
    atomicAdd(&m[1], a2);
    atomicAdd(&m[2], a3);
    atomicAdd(&m[3], a4);
}

__global__ void finalize_k(const double* __restrict__ mom, const int* __restrict__ boff,
                           const float* __restrict__ W, float* __restrict__ out) {
    int i = blockIdx.x * blockDim.x + threadIdx.x;
    if (i < NB * NFEAT) {
        int b = i / NFEAT, f = i % NFEAT;
        double cn = (double)max(boff[b + 1] - boff[b], 1);
        const double* m = mom + ((size_t)b * NFEAT + f) * 4;
        double mean = m[0] / cn;
        double e2 = m[1] / cn, e3 = m[2] / cn, e4 = m[3] / cn;
        double var = e2 - mean * mean;
        double m3 = e3 - 3.0 * mean * e2 + 2.0 * mean * mean * mean;
        double m4 = e4 - 4.0 * mean * e3 + 6.0 * mean * mean * e2 - 3.0 * mean * mean * mean * mean;
        float skew, kurt;
        if (var > 0.0) {
            double vs = var * sqrt(var);
            skew = (float)(m3 / vs);
            kurt = (float)(m4 / (var * var));
        } else {
            skew = 0.f; kurt = -3.f;
        }
        out[b * 2816 + f]        = (float)mean;
        out[b * 2816 + 704 + f]  = (float)var;
        out[b * 2816 + 1408 + f] = skew;
        out[b * 2816 + 2112 + f] = kurt;
    } else if (i < NB * NFEAT + 68) {
        int j = i - NB * NFEAT;
        out[NB * 2816 + j] = W[j];
    }
}

// ---------------- launch ----------------

extern "C" void kernel_launch(void* const* d_in, const int* in_sizes, int n_in,
                              void* d_out, int out_size, void* d_ws, size_t ws_size,
                              hipStream_t stream) {
    const float* x     = (const float*)d_in[0];
    const int*   ei    = (const int*)d_in[1];
    const int*   batch = (const int*)d_in[2];
    const float* W     = (const float*)d_in[3];
    int N = in_sizes[0] / 64;   // 20000
    int E = in_sizes[1] / 2;    // 640000
    float* out = (float*)d_out;

    char* p = (char*)d_ws;
    auto alloc = [&](size_t bytes) { char* r = p; p += (bytes + 255) & ~255ULL; return r; };
    float* dinv  = (float*)alloc((size_t)N * 4);
    int*   cnt   = (int*)alloc((size_t)N * 4);
    int*   cursor= (int*)alloc((size_t)N * 4);
    int*   boff  = (int*)alloc((NB + 1) * 4);
    double* mom  = (double*)alloc((size_t)NB * NFEAT * 4 * 8);
    int2*  pairs = (int2*)alloc((size_t)N * CAP * 8);
    float* S1    = (float*)alloc((size_t)N * 256 * 4);
    float* S2    = (float*)alloc((size_t)N * 384 * 4);
    float* bufA  = (float*)alloc((size_t)N * 256 * 4);
    float* bufB  = (float*)alloc((size_t)N * 256 * 4);
    float* prev  = (float*)alloc((size_t)N * 256 * 4);

    hipMemsetAsync(cnt, 0, (size_t)N * 4, stream);
    hipMemsetAsync(cursor, 0, (size_t)N * 4, stream);
    hipMemsetAsync(mom, 0, (size_t)NB * NFEAT * 4 * 8, stream);

    count_edges<<<(E + 255) / 256, 256, 0, stream>>>(ei, E, cnt);
    compute_dinv<<<(N + 255) / 256, 256, 0, stream>>>(cnt, dinv, N);
    fill_edges<<<(E + 255) / 256, 256, 0, stream>>>(ei, E, dinv, cursor, pairs);
    batch_bounds<<<(N + 255) / 256, 256, 0, stream>>>(batch, N, boff);

    int cgrid = (N + 3) / 4;  // 4 waves (nodes) per 256-thread block

    // ---- level 1: F=64, h0 = x; snapshots at 1,2,4,8,16 ----
    const float* hin = x;
    for (int s = 1; s <= 16; ++s) {
        float* ho = (s & 1) ? bufA : bufB;
        cascade_step<64><<<cgrid, 256, 0, stream>>>(hin, ho, pairs, cnt, dinv, N);
        hin = ho;
        if (s == 1) {
            copyk<<<(N * 64 + 255) / 256, 256, 0, stream>>>(ho, prev, N * 64);
        } else if (s == 2 || s == 4 || s == 8 || s == 16) {
            int w = (s == 2) ? 0 : (s == 4) ? 1 : (s == 8) ? 2 : 3;
            diff1<<<(N * 64 + 255) / 256, 256, 0, stream>>>(ho, prev, S1, w, N * 64);
        }
    }

    // ---- level 2: F=256, h0 = S1; diffs at 4,8,16 (w=1,2,3), snapshot base at 2 ----
    hin = S1;
    for (int s = 1; s <= 16; ++s) {
        float* ho = (s & 1) ? bufA : bufB;
        cascade_step<256><<<cgrid, 256, 0, stream>>>(hin, ho, pairs, cnt, dinv, N);
        hin = ho;
        if (s == 2) {
            copyk<<<(N * 256 + 255) / 256, 256, 0, stream>>>(ho, prev, N * 256);
        } else if (s == 4 || s == 8 || s == 16) {
            int w = (s == 4) ? 1 : (s == 8) ? 2 : 3;
            int basej = (w == 1) ? 0 : (w == 2) ? 1 : 3;
            diff2<<<(N * 256 + 255) / 256, 256, 0, stream>>>(ho, prev, S2, w, basej, N * 256);
        }
    }

    moments_k<<<NB * 3 * NSLICE, 256, 0, stream>>>(x, S1, S2, boff, mom);

    int fin_threads = NB * NFEAT + 68;
    finalize_k<<<(fin_threads + 255) / 256, 256, 0, stream>>>(mom, boff, W, out);
}

// Round 3
// 1391.102 us; speedup vs baseline: 1.7380x; 1.3308x over previous
//
#include <hip/hip_runtime.h>
#include <hip/hip_bf16.h>

#define NB 8
#define CAP 128
#define NSLICE 16
#define NFEAT 704

// ---------------- setup kernels ----------------

__global__ void count_edges(const int* __restrict__ ei, int E, int* __restrict__ cnt) {
    int e = blockIdx.x * blockDim.x + threadIdx.x;
    if (e < E) atomicAdd(&cnt[ei[E + e]], 1);
}

__global__ void compute_dinv(const int* __restrict__ cnt, float* __restrict__ dinv, int n) {
    int v = blockIdx.x * blockDim.x + threadIdx.x;
    if (v < n) dinv[v] = rsqrtf((float)(cnt[v] + 1));  // +1 self-loop; always > 0
}

__global__ void fill_edges(const int* __restrict__ ei, int E, const float* __restrict__ dinv,
                           int* __restrict__ cursor, int2* __restrict__ pairs) {
    int e = blockIdx.x * blockDim.x + threadIdx.x;
    if (e < E) {
        int r = ei[e], c = ei[E + e];
        int pos = atomicAdd(&cursor[c], 1);
        if (pos < CAP) {
            float w = dinv[r] * dinv[c];
            pairs[(size_t)c * CAP + pos] = make_int2(r, __float_as_int(w));
        }
    }
}

// batch is SORTED: find boundaries, no atomics. boff[b] = first index with batch >= b.
__global__ void batch_bounds(const int* __restrict__ batch, int n, int* __restrict__ boff) {
    int i = blockIdx.x * blockDim.x + threadIdx.x;
    if (i >= n) return;
    int b = batch[i];
    int pb = (i == 0) ? -1 : batch[i - 1];
    for (int k = pb + 1; k <= b; ++k) boff[k] = i;
    if (i == n - 1) {
        for (int k = b + 1; k <= NB; ++k) boff[k] = n;
    }
}

// ---------------- cascade (64 channels, one wave per node) ----------------
// h_out[v][c] = 0.5*((1 + dinv[v]^2) * h_in[v][c] + sum_e w_e * h_in[src_e][c])
// Pair list is wave-uniform -> scalar loads; gather = SGPR base + lane offset.
// mode: 0 = none, 1 = snapshot (prev = v), 2 = diff (write |v - prev|, prev = v)

__global__ __launch_bounds__(256) void cascade64(
    const float* __restrict__ h_in, int in_stride, int in_off,
    float* __restrict__ h_out,
    const int2* __restrict__ pairs, const int* __restrict__ cnt,
    const float* __restrict__ dinv, int n,
    int mode, float* __restrict__ prev,
    float* __restrict__ diff_out, int diff_stride, int diff_off)
{
    int wave = (blockIdx.x * blockDim.x + threadIdx.x) >> 6;
    int lane = threadIdx.x & 63;
    if (wave >= n) return;
    int node = __builtin_amdgcn_readfirstlane(wave);
    int deg = cnt[node];
    float dv = dinv[node];
    float selfw = 1.f + dv * dv;

    const float* hrow = h_in + (size_t)node * in_stride + in_off;
    float hv = hrow[lane];

    const int2* pb = pairs + (size_t)node * CAP;
    float acc0 = 0.f, acc1 = 0.f, acc2 = 0.f, acc3 = 0.f;
    int j = 0;
    for (; j + 8 <= deg; j += 8) {
        int4 q0 = *reinterpret_cast<const int4*>(pb + j);
        int4 q1 = *reinterpret_cast<const int4*>(pb + j + 2);
        int4 q2 = *reinterpret_cast<const int4*>(pb + j + 4);
        int4 q3 = *reinterpret_cast<const int4*>(pb + j + 6);
        const float* r0 = h_in + (size_t)q0.x * in_stride + in_off;
        const float* r1 = h_in + (size_t)q0.z * in_stride + in_off;
        const float* r2 = h_in + (size_t)q1.x * in_stride + in_off;
        const float* r3 = h_in + (size_t)q1.z * in_stride + in_off;
        const float* r4 = h_in + (size_t)q2.x * in_stride + in_off;
        const float* r5 = h_in + (size_t)q2.z * in_stride + in_off;
        const float* r6 = h_in + (size_t)q3.x * in_stride + in_off;
        const float* r7 = h_in + (size_t)q3.z * in_stride + in_off;
        float g0 = r0[lane], g1 = r1[lane], g2 = r2[lane], g3 = r3[lane];
        float g4 = r4[lane], g5 = r5[lane], g6 = r6[lane], g7 = r7[lane];
        acc0 += __int_as_float(q0.y) * g0; acc1 += __int_as_float(q0.w) * g1;
        acc2 += __int_as_float(q1.y) * g2; acc3 += __int_as_float(q1.w) * g3;
        acc0 += __int_as_float(q2.y) * g4; acc1 += __int_as_float(q2.w) * g5;
        acc2 += __int_as_float(q3.y) * g6; acc3 += __int_as_float(q3.w) * g7;
    }
    for (; j < deg; ++j) {
        int2 p = pb[j];
        const float* r = h_in + (size_t)p.x * in_stride + in_off;
        acc0 += __int_as_float(p.y) * r[lane];
    }
    float v = 0.5f * (selfw * hv + ((acc0 + acc1) + (acc2 + acc3)));
    size_t oidx = (size_t)node * 64 + lane;
    h_out[oidx] = v;
    if (mode == 1) {
        prev[oidx] = v;
    } else if (mode == 2) {
        float p = prev[oidx];
        prev[oidx] = v;
        diff_out[(size_t)node * diff_stride + diff_off + lane] = fabsf(v - p);
    }
}

// ---------------- moments ----------------

__global__ __launch_bounds__(256) void moments_k(
    const float* __restrict__ x, const float* __restrict__ S1, const float* __restrict__ S2,
    const int* __restrict__ boff, double* __restrict__ mom)
{
    int bid = blockIdx.x;                 // b * (3*NSLICE) + chunk * NSLICE + slice
    int slice = bid % NSLICE;
    int chunk = (bid / NSLICE) % 3;
    int b = bid / (3 * NSLICE);
    int f = chunk * 256 + threadIdx.x;
    if (f >= NFEAT) return;
    int k = f >> 6, c = f & 63;
    const float* base; int stride;
    if (k == 0)      { base = x  + c;                stride = 64;  }
    else if (k <= 4) { base = S1 + (k - 1) * 64 + c; stride = 256; }
    else             { base = S2 + (k - 5) * 64 + c; stride = 384; }

    int s0 = boff[b], s1e = boff[b + 1];
    int cnt = s1e - s0;
    int per = (cnt + NSLICE - 1) / NSLICE;
    int i0 = s0 + slice * per;
    int i1 = min(s1e, i0 + per);

    double a1 = 0, a2 = 0, a3 = 0, a4 = 0;
    for (int i = i0; i < i1; ++i) {
        double v = (double)base[(size_t)i * stride];
        double v2 = v * v;
        a1 += v; a2 += v2; a3 += v2 * v; a4 += v2 * v2;
    }
    double* m = mom + ((size_t)b * NFEAT + f) * 4;
    atomicAdd(&m[0], a1);
    atomicAdd(&m[1], a2);
    atomicAdd(&m[2], a3);
    atomicAdd(&m[3], a4);
}

__global__ void finalize_k(const double* __restrict__ mom, const int* __restrict__ boff,
                           const float* __restrict__ W, float* __restrict__ out) {
    int i = blockIdx.x * blockDim.x + threadIdx.x;
    if (i < NB * NFEAT) {
        int b = i / NFEAT, f = i % NFEAT;
        double cn = (double)max(boff[b + 1] - boff[b], 1);
        const double* m = mom + ((size_t)b * NFEAT + f) * 4;
        double mean = m[0] / cn;
        double e2 = m[1] / cn, e3 = m[2] / cn, e4 = m[3] / cn;
        double var = e2 - mean * mean;
        double m3 = e3 - 3.0 * mean * e2 + 2.0 * mean * mean * mean;
        double m4 = e4 - 4.0 * mean * e3 + 6.0 * mean * mean * e2 - 3.0 * mean * mean * mean * mean;
        float skew, kurt;
        if (var > 0.0) {
            double vs = var * sqrt(var);
            skew = (float)(m3 / vs);
            kurt = (float)(m4 / (var * var));
        } else {
            skew = 0.f; kurt = -3.f;
        }
        out[b * 2816 + f]        = (float)mean;
        out[b * 2816 + 704 + f]  = (float)var;
        out[b * 2816 + 1408 + f] = skew;
        out[b * 2816 + 2112 + f] = kurt;
    } else if (i < NB * NFEAT + 68) {
        int j = i - NB * NFEAT;
        out[NB * 2816 + j] = W[j];
    }
}

// ---------------- launch ----------------

extern "C" void kernel_launch(void* const* d_in, const int* in_sizes, int n_in,
                              void* d_out, int out_size, void* d_ws, size_t ws_size,
                              hipStream_t stream) {
    const float* x     = (const float*)d_in[0];
    const int*   ei    = (const int*)d_in[1];
    const int*   batch = (const int*)d_in[2];
    const float* W     = (const float*)d_in[3];
    int N = in_sizes[0] / 64;   // 20000
    int E = in_sizes[1] / 2;    // 640000
    float* out = (float*)d_out;

    char* p = (char*)d_ws;
    auto alloc = [&](size_t bytes) { char* r = p; p += (bytes + 255) & ~255ULL; return r; };
    float* dinv  = (float*)alloc((size_t)N * 4);
    int*   cnt   = (int*)alloc((size_t)N * 4);
    int*   cursor= (int*)alloc((size_t)N * 4);
    int*   boff  = (int*)alloc((NB + 1) * 4);
    double* mom  = (double*)alloc((size_t)NB * NFEAT * 4 * 8);
    int2*  pairs = (int2*)alloc((size_t)N * CAP * 8);
    float* S1    = (float*)alloc((size_t)N * 256 * 4);
    float* S2    = (float*)alloc((size_t)N * 384 * 4);
    float* bufA  = (float*)alloc((size_t)N * 64 * 4);
    float* bufB  = (float*)alloc((size_t)N * 64 * 4);
    float* prev  = (float*)alloc((size_t)N * 64 * 4);

    hipMemsetAsync(cnt, 0, (size_t)N * 4, stream);
    hipMemsetAsync(cursor, 0, (size_t)N * 4, stream);
    hipMemsetAsync(mom, 0, (size_t)NB * NFEAT * 4 * 8, stream);

    count_edges<<<(E + 255) / 256, 256, 0, stream>>>(ei, E, cnt);
    compute_dinv<<<(N + 255) / 256, 256, 0, stream>>>(cnt, dinv, N);
    fill_edges<<<(E + 255) / 256, 256, 0, stream>>>(ei, E, dinv, cursor, pairs);
    batch_bounds<<<(N + 255) / 256, 256, 0, stream>>>(batch, N, boff);

    int cgrid = (N + 3) / 4;  // 4 waves (nodes) per 256-thread block

    // ---- level 1: F=64 cascade on x; snap at s=1; diffs at 2,4,8,16 -> S1[w] ----
    {
        const float* hin = x; int istride = 64, ioff = 0;
        for (int s = 1; s <= 16; ++s) {
            float* ho = (s & 1) ? bufA : bufB;
            int mode = 0; float* dout = nullptr; int doff = 0;
            if (s == 1) mode = 1;
            else if (s == 2 || s == 4 || s == 8 || s == 16) {
                mode = 2; dout = S1;
                int w = (s == 2) ? 0 : (s == 4) ? 1 : (s == 8) ? 2 : 3;
                doff = w * 64;
            }
            cascade64<<<cgrid, 256, 0, stream>>>(hin, istride, ioff, ho, pairs, cnt, dinv, N,
                                                 mode, prev, dout, 256, doff);
            hin = ho; istride = 64; ioff = 0;
        }
    }

    // ---- level 2: three independent 64-ch cascades on S1 blocks b=0,1,2 ----
    // S2 slots (stride 384): j0=(w1,b0) j1=(w2,b0) j2=(w2,b1) j3=(w3,b0) j4=(w3,b1) j5=(w3,b2)
    for (int b = 0; b < 3; ++b) {
        int snap_step = (b == 0) ? 2 : (b == 1) ? 4 : 8;
        const float* hin = S1; int istride = 256, ioff = b * 64;
        for (int s = 1; s <= 16; ++s) {
            float* ho = (s & 1) ? bufA : bufB;
            int mode = 0; float* dout = nullptr; int doff = 0;
            if (s == snap_step) mode = 1;
            else if (s > snap_step && (s == 4 || s == 8 || s == 16)) {
                mode = 2; dout = S2;
                int slot;
                if (b == 0)      slot = (s == 4) ? 0 : (s == 8) ? 1 : 3;
                else if (b == 1) slot = (s == 8) ? 2 : 4;
                else             slot = 5;
                doff = slot * 64;
            }
            cascade64<<<cgrid, 256, 0, stream>>>(hin, istride, ioff, ho, pairs, cnt, dinv, N,
                                                 mode, prev, dout, 384, doff);
            hin = ho; istride = 64; ioff = 0;
        }
    }

    moments_k<<<NB * 3 * NSLICE, 256, 0, stream>>>(x, S1, S2, boff, mom);

    int fin_threads = NB * NFEAT + 68;
    finalize_k<<<(fin_threads + 255) / 256, 256, 0, stream>>>(mom, boff, W, out);
}

// Round 4
// 1244.100 us; speedup vs baseline: 1.9434x; 1.1182x over previous
//
#include <hip/hip_runtime.h>
#include <hip/hip_bf16.h>

#define NB 8
#define CAP 128
#define NSLICE 64
#define NFEAT 704

// ---------------- setup kernels ----------------

__global__ void count_edges(const int* __restrict__ ei, int E, int* __restrict__ cnt) {
    int e = blockIdx.x * blockDim.x + threadIdx.x;
    if (e < E) atomicAdd(&cnt[ei[E + e]], 1);
}

__global__ void compute_dinv(const int* __restrict__ cnt, float* __restrict__ dinv, int n) {
    int v = blockIdx.x * blockDim.x + threadIdx.x;
    if (v < n) dinv[v] = rsqrtf((float)(cnt[v] + 1));  // +1 self-loop; always > 0
}

__global__ void fill_edges(const int* __restrict__ ei, int E, const float* __restrict__ dinv,
                           int* __restrict__ cursor, int2* __restrict__ pairs) {
    int e = blockIdx.x * blockDim.x + threadIdx.x;
    if (e < E) {
        int r = ei[e], c = ei[E + e];
        int pos = atomicAdd(&cursor[c], 1);
        if (pos < CAP) {
            float w = dinv[r] * dinv[c];
            pairs[(size_t)c * CAP + pos] = make_int2(r, __float_as_int(w));
        }
    }
}

// pad each node's edge list to a multiple of 4 with zero-weight edges -> src 0, w 0
__global__ void pad_edges(const int* __restrict__ cnt, int2* __restrict__ pairs, int n) {
    int v = blockIdx.x * blockDim.x + threadIdx.x;
    if (v >= n) return;
    int c = min(cnt[v], CAP);
    int c4 = (c + 3) & ~3;
    for (int j = c; j < c4; ++j) pairs[(size_t)v * CAP + j] = make_int2(0, 0);
}

// batch is SORTED: find boundaries, no atomics. boff[b] = first index with batch >= b.
__global__ void batch_bounds(const int* __restrict__ batch, int n, int* __restrict__ boff) {
    int i = blockIdx.x * blockDim.x + threadIdx.x;
    if (i >= n) return;
    int b = batch[i];
    int pb = (i == 0) ? -1 : batch[i - 1];
    for (int k = pb + 1; k <= b; ++k) boff[k] = i;
    if (i == n - 1) {
        for (int k = b + 1; k <= NB; ++k) boff[k] = n;
    }
}

// ---------------- cascade (64 channels, one wave per node) ----------------
// h_out[v][c] = 0.5*((1 + dinv[v]^2) * h_in[v][c] + sum_e w_e * h_in[src_e][c])
// Lane l handles edge j + l/16, channels (l%16)*4 .. +3 (float4 gather: 4 edges
// per vmem instr). Pair data via wave-uniform scalar loads + cndmask select.
// blockIdx.y = sub-cascade b (level 2 runs 3 independent 64-ch cascades).
// mode per b: 0 = none, 1 = snapshot (prev = v), 2 = diff (|v - prev| -> S, prev = v)

__global__ __launch_bounds__(256) void cascade64(
    const float* __restrict__ h_in, int in_stride, int in_off, long in_sub,
    float* __restrict__ h_out, long out_sub,
    const int2* __restrict__ pairs, const int* __restrict__ cnt,
    const float* __restrict__ dinv, int n,
    int modes, int slots, float* __restrict__ prev, long prev_sub,
    float* __restrict__ diff_out, int diff_stride)
{
    int wave = (blockIdx.x * blockDim.x + threadIdx.x) >> 6;
    int lane = threadIdx.x & 63;
    if (wave >= n) return;
    int node = __builtin_amdgcn_readfirstlane(wave);
    int b = blockIdx.y;
    int mode = (modes >> (b * 4)) & 15;
    int slot = (slots >> (b * 8)) & 255;

    int deg = min(cnt[node], CAP);
    int deg4 = (deg + 3) & ~3;
    float dv = dinv[node];
    float selfw = 1.f + dv * dv;

    const float* hb = h_in + in_sub * b + in_off;
    int sub = lane >> 4;        // which of 4 edges in the group
    int cg  = lane & 15;        // channel group: channels cg*4 .. cg*4+3

    const int2* pb = pairs + (size_t)node * CAP;
    float4 acc = make_float4(0.f, 0.f, 0.f, 0.f);

    int j = 0;
    for (; j + 8 <= deg4; j += 8) {
        int4 q0 = *reinterpret_cast<const int4*>(pb + j);
        int4 q1 = *reinterpret_cast<const int4*>(pb + j + 2);
        int4 q2 = *reinterpret_cast<const int4*>(pb + j + 4);
        int4 q3 = *reinterpret_cast<const int4*>(pb + j + 6);
        int   sA = sub < 2 ? (sub == 0 ? q0.x : q0.z) : (sub == 2 ? q1.x : q1.z);
        float wA = __int_as_float(sub < 2 ? (sub == 0 ? q0.y : q0.w) : (sub == 2 ? q1.y : q1.w));
        int   sB = sub < 2 ? (sub == 0 ? q2.x : q2.z) : (sub == 2 ? q3.x : q3.z);
        float wB = __int_as_float(sub < 2 ? (sub == 0 ? q2.y : q2.w) : (sub == 2 ? q3.y : q3.w));
        float4 gA = *reinterpret_cast<const float4*>(hb + (size_t)sA * in_stride + cg * 4);
        float4 gB = *reinterpret_cast<const float4*>(hb + (size_t)sB * in_stride + cg * 4);
        acc.x += wA * gA.x; acc.y += wA * gA.y; acc.z += wA * gA.z; acc.w += wA * gA.w;
        acc.x += wB * gB.x; acc.y += wB * gB.y; acc.z += wB * gB.z; acc.w += wB * gB.w;
    }
    if (j < deg4) {  // one remaining group of 4
        int4 q0 = *reinterpret_cast<const int4*>(pb + j);
        int4 q1 = *reinterpret_cast<const int4*>(pb + j + 2);
        int   sA = sub < 2 ? (sub == 0 ? q0.x : q0.z) : (sub == 2 ? q1.x : q1.z);
        float wA = __int_as_float(sub < 2 ? (sub == 0 ? q0.y : q0.w) : (sub == 2 ? q1.y : q1.w));
        float4 gA = *reinterpret_cast<const float4*>(hb + (size_t)sA * in_stride + cg * 4);
        acc.x += wA * gA.x; acc.y += wA * gA.y; acc.z += wA * gA.z; acc.w += wA * gA.w;
    }

    // reduce the 4 edge-phases (lanes cg, cg+16, cg+32, cg+48 hold same channels)
#pragma unroll
    for (int m = 16; m <= 32; m <<= 1) {
        acc.x += __shfl_xor(acc.x, m, 64);
        acc.y += __shfl_xor(acc.y, m, 64);
        acc.z += __shfl_xor(acc.z, m, 64);
        acc.w += __shfl_xor(acc.w, m, 64);
    }

    if (lane < 16) {
        const float4 hv = *reinterpret_cast<const float4*>(hb + (size_t)node * in_stride + cg * 4);
        float4 v;
        v.x = 0.5f * (selfw * hv.x + acc.x);
        v.y = 0.5f * (selfw * hv.y + acc.y);
        v.z = 0.5f * (selfw * hv.z + acc.z);
        v.w = 0.5f * (selfw * hv.w + acc.w);
        float* orow = h_out + out_sub * b + (size_t)node * 64 + cg * 4;
        *reinterpret_cast<float4*>(orow) = v;
        if (mode) {
            float* prow = prev + prev_sub * b + (size_t)node * 64 + cg * 4;
            if (mode == 1) {
                *reinterpret_cast<float4*>(prow) = v;
            } else {
                float4 pv = *reinterpret_cast<const float4*>(prow);
                *reinterpret_cast<float4*>(prow) = v;
                float4 d;
                d.x = fabsf(v.x - pv.x); d.y = fabsf(v.y - pv.y);
                d.z = fabsf(v.z - pv.z); d.w = fabsf(v.w - pv.w);
                float* drow = diff_out + (size_t)node * diff_stride + slot * 64 + cg * 4;
                *reinterpret_cast<float4*>(drow) = d;
            }
        }
    }
}

// ---------------- moments ----------------

__global__ __launch_bounds__(256) void moments_k(
    const float* __restrict__ x, const float* __restrict__ S1, const float* __restrict__ S2,
    const int* __restrict__ boff, double* __restrict__ mom)
{
    int bid = blockIdx.x;                 // b * (3*NSLICE) + chunk * NSLICE + slice
    int slice = bid % NSLICE;
    int chunk = (bid / NSLICE) % 3;
    int b = bid / (3 * NSLICE);
    int f = chunk * 256 + threadIdx.x;
    if (f >= NFEAT) return;
    int k = f >> 6, c = f & 63;
    const float* base; int stride;
    if (k == 0)      { base = x  + c;                stride = 64;  }
    else if (k <= 4) { base = S1 + (k - 1) * 64 + c; stride = 256; }
    else             { base = S2 + (k - 5) * 64 + c; stride = 384; }

    int s0 = boff[b], s1e = boff[b + 1];
    int cnt = s1e - s0;
    int per = (cnt + NSLICE - 1) / NSLICE;
    int i0 = s0 + slice * per;
    int i1 = min(s1e, i0 + per);

    double a1 = 0, a2 = 0, a3 = 0, a4 = 0;
    for (int i = i0; i < i1; ++i) {
        double v = (double)base[(size_t)i * stride];
        double v2 = v * v;
        a1 += v; a2 += v2; a3 += v2 * v; a4 += v2 * v2;
    }
    double* m = mom + ((size_t)b * NFEAT + f) * 4;
    atomicAdd(&m[0], a1);
    atomicAdd(&m[1], a2);
    atomicAdd(&m[2], a3);
    atomicAdd(&m[3], a4);
}

__global__ void finalize_k(const double* __restrict__ mom, const int* __restrict__ boff,
                           const float* __restrict__ W, float* __restrict__ out) {
    int i = blockIdx.x * blockDim.x + threadIdx.x;
    if (i < NB * NFEAT) {
        int b = i / NFEAT, f = i % NFEAT;
        double cn = (double)max(boff[b + 1] - boff[b], 1);
        const double* m = mom + ((size_t)b * NFEAT + f) * 4;
        double mean = m[0] / cn;
        double e2 = m[1] / cn, e3 = m[2] / cn, e4 = m[3] / cn;
        double var = e2 - mean * mean;
        double m3 = e3 - 3.0 * mean * e2 + 2.0 * mean * mean * mean;
        double m4 = e4 - 4.0 * mean * e3 + 6.0 * mean * mean * e2 - 3.0 * mean * mean * mean * mean;
        float skew, kurt;
        if (var > 0.0) {
            double vs = var * sqrt(var);
            skew = (float)(m3 / vs);
            kurt = (float)(m4 / (var * var));
        } else {
            skew = 0.f; kurt = -3.f;
        }
        out[b * 2816 + f]        = (float)mean;
        out[b * 2816 + 704 + f]  = (float)var;
        out[b * 2816 + 1408 + f] = skew;
        out[b * 2816 + 2112 + f] = kurt;
    } else if (i < NB * NFEAT + 68) {
        int j = i - NB * NFEAT;
        out[NB * 2816 + j] = W[j];
    }
}

// ---------------- launch ----------------

extern "C" void kernel_launch(void* const* d_in, const int* in_sizes, int n_in,
                              void* d_out, int out_size, void* d_ws, size_t ws_size,
                              hipStream_t stream) {
    const float* x     = (const float*)d_in[0];
    const int*   ei    = (const int*)d_in[1];
    const int*   batch = (const int*)d_in[2];
    const float* W     = (const float*)d_in[3];
    int N = in_sizes[0] / 64;   // 20000
    int E = in_sizes[1] / 2;    // 640000
    float* out = (float*)d_out;

    char* p = (char*)d_ws;
    auto alloc = [&](size_t bytes) { char* r = p; p += (bytes + 255) & ~255ULL; return r; };
    float* dinv  = (float*)alloc((size_t)N * 4);
    int*   cnt   = (int*)alloc((size_t)N * 4);
    int*   cursor= (int*)alloc((size_t)N * 4);
    int*   boff  = (int*)alloc((NB + 1) * 4);
    double* mom  = (double*)alloc((size_t)NB * NFEAT * 4 * 8);
    int2*  pairs = (int2*)alloc((size_t)N * CAP * 8);
    float* S1    = (float*)alloc((size_t)N * 256 * 4);
    float* S2    = (float*)alloc((size_t)N * 384 * 4);
    long   sub   = (long)N * 64;                       // per-sub-cascade element stride
    float* bufA  = (float*)alloc((size_t)3 * N * 64 * 4);
    float* bufB  = (float*)alloc((size_t)3 * N * 64 * 4);
    float* prev  = (float*)alloc((size_t)3 * N * 64 * 4);

    hipMemsetAsync(cnt, 0, (size_t)N * 4, stream);
    hipMemsetAsync(cursor, 0, (size_t)N * 4, stream);
    hipMemsetAsync(mom, 0, (size_t)NB * NFEAT * 4 * 8, stream);

    count_edges<<<(E + 255) / 256, 256, 0, stream>>>(ei, E, cnt);
    compute_dinv<<<(N + 255) / 256, 256, 0, stream>>>(cnt, dinv, N);
    fill_edges<<<(E + 255) / 256, 256, 0, stream>>>(ei, E, dinv, cursor, pairs);
    pad_edges<<<(N + 255) / 256, 256, 0, stream>>>(cnt, pairs, N);
    batch_bounds<<<(N + 255) / 256, 256, 0, stream>>>(batch, N, boff);

    dim3 cgrid1((N + 3) / 4, 1);
    dim3 cgrid3((N + 3) / 4, 3);

    // ---- level 1: 64-ch cascade on x; snap at s=1; diffs at 2,4,8,16 -> S1[w] ----
    {
        const float* hin = x; int istride = 64, ioff = 0;
        for (int s = 1; s <= 16; ++s) {
            float* ho = (s & 1) ? bufA : bufB;
            int mode = 0, slot = 0;
            if (s == 1) mode = 1;
            else if (s == 2 || s == 4 || s == 8 || s == 16) {
                mode = 2;
                slot = (s == 2) ? 0 : (s == 4) ? 1 : (s == 8) ? 2 : 3;
            }
            cascade64<<<cgrid1, 256, 0, stream>>>(hin, istride, ioff, 0L, ho, 0L,
                                                  pairs, cnt, dinv, N,
                                                  mode, slot, prev, 0L, S1, 256);
            hin = ho; istride = 64; ioff = 0;
        }
    }

    // ---- level 2: three independent 64-ch cascades on S1 blocks b=0,1,2 (one dispatch/step) ----
    // per b: snap at {2,4,8}; diffs: b0 -> s4:slot0, s8:slot1, s16:slot3; b1 -> s8:slot2, s16:slot4; b2 -> s16:slot5
    {
        const float* hin = S1; int istride = 256, ioff = 0; long isub = 64;
        for (int s = 1; s <= 16; ++s) {
            float* ho = (s & 1) ? bufA : bufB;
            int m0 = (s == 2) ? 1 : (s == 4 || s == 8 || s == 16) ? 2 : 0;
            int m1 = (s == 4) ? 1 : (s == 8 || s == 16) ? 2 : 0;
            int m2 = (s == 8) ? 1 : (s == 16) ? 2 : 0;
            int sl0 = (s == 4) ? 0 : (s == 8) ? 1 : 3;
            int sl1 = (s == 8) ? 2 : 4;
            int sl2 = 5;
            int modes = m0 | (m1 << 4) | (m2 << 8);
            int slots = sl0 | (sl1 << 8) | (sl2 << 16);
            cascade64<<<cgrid3, 256, 0, stream>>>(hin, istride, ioff, isub, ho, sub,
                                                  pairs, cnt, dinv, N,
                                                  modes, slots, prev, sub, S2, 384);
            hin = ho; istride = 64; ioff = 0; isub = sub;
        }
    }

    moments_k<<<NB * 3 * NSLICE, 256, 0, stream>>>(x, S1, S2, boff, mom);

    int fin_threads = NB * NFEAT + 68;
    finalize_k<<<(fin_threads + 255) / 256, 256, 0, stream>>>(mom, boff, W, out);
}